// Round 1
// baseline (321.414 us; speedup 1.0000x reference)
//
#include <hip/hip_runtime.h>
#include <hip/hip_bf16.h>
#include <math.h>

// Problem constants
#define NHEADS 16
#define HDIM   64
#define SEQT   2048
#define NBATCH 4
#define DMODEL 1024
#define MROWS  (NBATCH * SEQT)   // 8192

typedef __bf16 bf16;
typedef bf16  bf16x8 __attribute__((ext_vector_type(8)));
typedef float f32x4  __attribute__((ext_vector_type(4)));

#define MFMA_BF16(a, b, c) __builtin_amdgcn_mfma_f32_16x16x32_bf16((a), (b), (c), 0, 0, 0)

__device__ __forceinline__ void gload_lds16(const void* g, void* l) {
  __builtin_amdgcn_global_load_lds((const __attribute__((address_space(1))) void*)g,
                                   (__attribute__((address_space(3))) void*)l, 16, 0, 0);
}

// ---------------- conversion / transpose pre-passes ----------------

__global__ __launch_bounds__(256) void k_cvt_f32_bf16(const float* __restrict__ in,
                                                      bf16* __restrict__ out, int n8) {
  int i = blockIdx.x * blockDim.x + threadIdx.x;
  if (i >= n8) return;
  const float4* in4 = (const float4*)in;
  float4 a = in4[(size_t)i * 2], b = in4[(size_t)i * 2 + 1];
  bf16x8 v;
  v[0] = (bf16)a.x; v[1] = (bf16)a.y; v[2] = (bf16)a.z; v[3] = (bf16)a.w;
  v[4] = (bf16)b.x; v[5] = (bf16)b.y; v[6] = (bf16)b.z; v[7] = (bf16)b.w;
  *(bf16x8*)(out + (size_t)i * 8) = v;
}

// in [R][C] f32  ->  out [C][R] bf16 ; tile 64x64 ; grid = (R/64)*(C/64)
__global__ __launch_bounds__(256) void k_transpose_f32_bf16(const float* __restrict__ in,
                                                            bf16* __restrict__ out,
                                                            int R, int C) {
  int nct = C >> 6;
  int rt = blockIdx.x / nct, ct = blockIdx.x % nct;
  __shared__ float tile[64][65];
  int tid = threadIdx.x;
#pragma unroll
  for (int i = 0; i < 16; i++) {
    int e = i * 256 + tid, r = e >> 6, c = e & 63;
    tile[r][c] = in[(size_t)(rt * 64 + r) * C + ct * 64 + c];
  }
  __syncthreads();
#pragma unroll
  for (int i = 0; i < 16; i++) {
    int e = i * 256 + tid, r = e >> 6, c = e & 63;
    out[(size_t)(ct * 64 + r) * R + rt * 64 + c] = (bf16)tile[c][r];
  }
}

// v: [BH][T][64] bf16 -> vt: [BH][64][T] bf16 ; tile 64x64 ; grid = BH*(T/64)
__global__ __launch_bounds__(256) void k_transpose_v(const bf16* __restrict__ v,
                                                     bf16* __restrict__ vt) {
  int tt = blockIdx.x & 31;     // T/64 = 32
  int bh = blockIdx.x >> 5;
  __shared__ bf16 tile[64][65];
  int tid = threadIdx.x;
  const bf16* src = v + (size_t)bh * SEQT * 64 + (size_t)tt * 64 * 64;
#pragma unroll
  for (int i = 0; i < 16; i++) {
    int e = i * 256 + tid, r = e >> 6, c = e & 63;
    tile[r][c] = src[r * 64 + c];
  }
  __syncthreads();
  bf16* dst = vt + (size_t)bh * 64 * SEQT + tt * 64;
#pragma unroll
  for (int i = 0; i < 16; i++) {
    int e = i * 256 + tid, r = e >> 6, c = e & 63;   // r = d, c = t-within-tile
    dst[(size_t)r * SEQT + c] = tile[c][r];
  }
}

// ---------------- m97-structure 128x128 GEMM core (BK=32) ----------------
// A [M][K] bf16 row-major, Bt [N][K] bf16 row-major (i.e. B transposed).
// 256 threads = 4 waves in 2x2; each wave owns a 64x64 output sub-tile.

__device__ __forceinline__ void gemm128_core(const bf16* __restrict__ A,
                                             const bf16* __restrict__ Bt,
                                             int K, int bm, int bn, char* smem,
                                             f32x4 (&acc)[4][4]) {
  int tid = threadIdx.x, lane = tid & 63, w = tid >> 6;
  int l15 = lane & 15, g = lane >> 4;
  int wrow = (w >> 1) * 64, wcol = (w & 1) * 64;
  char* As = smem;
  char* Bs = smem + 8192;
  const char* Ag = (const char*)(A + (size_t)bm * 128 * K);
  const char* Bg = (const char*)(Bt + (size_t)bn * 128 * K);
  const int rowB = K * 2;               // global row stride in bytes
  int srow = w * 16 + (lane >> 2);      // row within 64-row issue chunk
  int scol = (lane & 3) * 16;           // byte within 64B LDS row

  for (int kt = 0; kt < K / 32; kt++) {
#pragma unroll
    for (int is = 0; is < 2; is++) {
      int row = is * 64 + srow;
      gload_lds16(Ag + (size_t)row * rowB + kt * 64 + scol, As + is * 4096 + w * 1024);
      gload_lds16(Bg + (size_t)row * rowB + kt * 64 + scol, Bs + is * 4096 + w * 1024);
    }
    __syncthreads();
    bf16x8 af[4], bfr[4];
#pragma unroll
    for (int i = 0; i < 4; i++)
      af[i] = *(const bf16x8*)&As[(wrow + i * 16 + l15) * 64 + g * 16];
#pragma unroll
    for (int j = 0; j < 4; j++)
      bfr[j] = *(const bf16x8*)&Bs[(wcol + j * 16 + l15) * 64 + g * 16];
#pragma unroll
    for (int i = 0; i < 4; i++)
#pragma unroll
      for (int j = 0; j < 4; j++)
        acc[i][j] = MFMA_BF16(af[i], bfr[j], acc[i][j]);
    __syncthreads();
  }
}

// QKV projection: A=xb [8192][1024], Bt=wqkvT [3072][1024], bias f32[3072].
// Epilogue scatters into Q/K/V, each [B*H][T][64] bf16.
__global__ __launch_bounds__(256) void k_gemm_qkv(const bf16* __restrict__ A,
                                                  const bf16* __restrict__ Bt,
                                                  const float* __restrict__ bias,
                                                  bf16* __restrict__ Qo,
                                                  bf16* __restrict__ Ko,
                                                  bf16* __restrict__ Vo) {
  const int K = DMODEL, NB = 24;        // N/128 = 3072/128
  int bm = blockIdx.x / NB, bn = blockIdx.x % NB;
  __shared__ __align__(16) char smem[16384];
  f32x4 acc[4][4] = {};
  gemm128_core(A, Bt, K, bm, bn, smem, acc);

  int tid = threadIdx.x, lane = tid & 63, w = tid >> 6;
  int l15 = lane & 15, g = lane >> 4;
  int wrow = (w >> 1) * 64, wcol = (w & 1) * 64;
  int rowbase = bm * 128 + wrow;
  int b = (bm * 128) >> 11;             // batch (T=2048 | 128-row blocks)
#pragma unroll
  for (int j = 0; j < 4; j++) {
    int n = bn * 128 + wcol + j * 16 + l15;      // 0..3071
    float bj = bias[n];
    int which = n >> 10;                          // 0=Q 1=K 2=V
    int nn = n & 1023;
    int head = nn >> 6, d = nn & 63;
    bf16* dst = (which == 0) ? Qo : (which == 1) ? Ko : Vo;
    size_t base = ((size_t)(b * NHEADS + head) * SEQT) * 64 + d;
#pragma unroll
    for (int i = 0; i < 4; i++) {
#pragma unroll
      for (int r = 0; r < 4; r++) {
        int row = rowbase + i * 16 + g * 4 + r;  // global m row
        int t = row & (SEQT - 1);
        dst[base + (size_t)t * 64] = (bf16)(acc[i][j][r] + bj);
      }
    }
  }
}

// Output projection: A=attn_out [8192][1024] bf16, Bt=woutT [1024][1024], out f32.
__global__ __launch_bounds__(256) void k_gemm_out(const bf16* __restrict__ A,
                                                  const bf16* __restrict__ Bt,
                                                  const float* __restrict__ bias,
                                                  float* __restrict__ C) {
  const int K = DMODEL, NB = 8;         // N/128 = 1024/128
  int bm = blockIdx.x / NB, bn = blockIdx.x % NB;
  __shared__ __align__(16) char smem[16384];
  f32x4 acc[4][4] = {};
  gemm128_core(A, Bt, K, bm, bn, smem, acc);

  int tid = threadIdx.x, lane = tid & 63, w = tid >> 6;
  int l15 = lane & 15, g = lane >> 4;
  int wrow = (w >> 1) * 64, wcol = (w & 1) * 64;
#pragma unroll
  for (int j = 0; j < 4; j++) {
    int n = bn * 128 + wcol + j * 16 + l15;
    float bj = bias[n];
#pragma unroll
    for (int i = 0; i < 4; i++) {
#pragma unroll
      for (int r = 0; r < 4; r++) {
        int row = bm * 128 + wrow + i * 16 + g * 4 + r;
        C[(size_t)row * DMODEL + n] = acc[i][j][r] + bj;
      }
    }
  }
}

// ---------------- flash attention (causal), bf16 MFMA ----------------
// Q,K: [BH][T][64] bf16 ; VT: [BH][64][T] bf16 ; out: [B*T][1024] bf16.
// Grid: (T/64) * BH, 256 threads = 4 waves; wave w owns q rows [qi*64+w*16, +16).
// KV tiles 64x64 staged via global_load_lds with XOR swizzle (row&7)<<4 applied
// to the GLOBAL source address (LDS dest stays linear), reads apply same XOR.

__global__ __launch_bounds__(256) void k_attn(const bf16* __restrict__ Q,
                                              const bf16* __restrict__ Kg,
                                              const bf16* __restrict__ VT,
                                              bf16* __restrict__ Oo) {
  int bh = blockIdx.x & 63;
  int qi = blockIdx.x >> 6;             // 0..31
  int tid = threadIdx.x, lane = tid & 63, w = tid >> 6;
  int l15 = lane & 15, g = lane >> 4;
  __shared__ __align__(16) char smem[24576];    // Ks 8K | Vs 8K | Ps 4x2K
  char* Ks = smem;
  char* Vs = smem + 8192;
  char* Ps = smem + 16384 + w * 2048;

  const bf16* Qbh = Q  + (size_t)bh * SEQT * 64;
  const bf16* Kbh = Kg + (size_t)bh * SEQT * 64;
  const bf16* Vbh = VT + (size_t)bh * 64 * SEQT;
  int qlo = qi * 64 + w * 16;

  // Q fragments, pre-scaled by 1/sqrt(64)=0.125 (exact in bf16)
  bf16x8 aq[2];
#pragma unroll
  for (int ks = 0; ks < 2; ks++) {
    bf16x8 v = *(const bf16x8*)(Qbh + (size_t)(qlo + l15) * 64 + ks * 32 + g * 8);
#pragma unroll
    for (int e = 0; e < 8; e++) v[e] = (bf16)((float)v[e] * 0.125f);
    aq[ks] = v;
  }

  float m[4], lsum[4];
  f32x4 o[4];
#pragma unroll
  for (int r = 0; r < 4; r++) { m[r] = -INFINITY; lsum[r] = 0.f; }
#pragma unroll
  for (int jd = 0; jd < 4; jd++) o[jd] = (f32x4){0.f, 0.f, 0.f, 0.f};

  for (int j = 0; j <= qi; j++) {
    // ---- stage K (contiguous 8KB) and VT tile (64 rows x 128B, stride T*2) ----
#pragma unroll
    for (int is = 0; is < 2; is++) {
      int p = is * 4096 + w * 1024 + (lane & 63) * 16;  // phys LDS byte offset
      int row = p >> 7;                                 // tile row (kv for K, d for V)
      int lg = p ^ ((row & 7) << 4);                    // logical byte (pre-swizzled src)
      gload_lds16((const char*)(Kbh + (size_t)j * 4096) + lg,
                  Ks + is * 4096 + w * 1024);
      int cb = lg & 127;
      gload_lds16((const char*)(Vbh + (size_t)row * SEQT + j * 64) + cb,
                  Vs + is * 4096 + w * 1024);
    }
    __syncthreads();

    // ---- S = (Q*scale) @ K^T : 4 column tiles of 16 kv each ----
    f32x4 s[4];
#pragma unroll
    for (int c = 0; c < 4; c++) {
      int row = c * 16 + l15;
      f32x4 t = {0.f, 0.f, 0.f, 0.f};
      t = MFMA_BF16(aq[0], *(const bf16x8*)&Ks[(row * 128 + 0  + g * 16) ^ ((l15 & 7) << 4)], t);
      t = MFMA_BF16(aq[1], *(const bf16x8*)&Ks[(row * 128 + 64 + g * 16) ^ ((l15 & 7) << 4)], t);
      s[c] = t;
    }

    // ---- causal mask + online softmax (rows live across 16 lanes of same g) ----
    bool diag = (j == qi);
    int qrb = w * 16 + g * 4;           // q row within 64-block, + r
#pragma unroll
    for (int r = 0; r < 4; r++) {
      float mx = -INFINITY;
#pragma unroll
      for (int c = 0; c < 4; c++) {
        float v = s[c][r];
        if (diag && (c * 16 + l15) > (qrb + r)) { v = -INFINITY; s[c][r] = v; }
        mx = fmaxf(mx, v);
      }
      mx = fmaxf(mx, __shfl_xor(mx, 1));
      mx = fmaxf(mx, __shfl_xor(mx, 2));
      mx = fmaxf(mx, __shfl_xor(mx, 4));
      mx = fmaxf(mx, __shfl_xor(mx, 8));
      float mn = fmaxf(m[r], mx);
      float co = __expf(m[r] - mn);
      m[r] = mn;
      float ssum = 0.f;
#pragma unroll
      for (int c = 0; c < 4; c++) {
        float p = __expf(s[c][r] - mn);
        s[c][r] = p;
        ssum += p;
      }
      ssum += __shfl_xor(ssum, 1);
      ssum += __shfl_xor(ssum, 2);
      ssum += __shfl_xor(ssum, 4);
      ssum += __shfl_xor(ssum, 8);
      lsum[r] = lsum[r] * co + ssum;
#pragma unroll
      for (int jd = 0; jd < 4; jd++) o[jd][r] *= co;
    }

    // ---- P -> per-wave LDS (bf16, swizzled) ----
#pragma unroll
    for (int c = 0; c < 4; c++) {
#pragma unroll
      for (int r = 0; r < 4; r++) {
        int row = g * 4 + r;
        int addr = (row * 128 + (c * 16 + l15) * 2) ^ ((row & 7) << 4);
        *(bf16*)&Ps[addr] = (bf16)s[c][r];
      }
    }

    // ---- O += P @ V ----
#pragma unroll
    for (int ks = 0; ks < 2; ks++) {
      bf16x8 pa = *(const bf16x8*)&Ps[(l15 * 128 + ks * 64 + g * 16) ^ ((l15 & 7) << 4)];
#pragma unroll
      for (int jd = 0; jd < 4; jd++) {
        int vrow = jd * 16 + l15;
        bf16x8 bv = *(const bf16x8*)&Vs[(vrow * 128 + ks * 64 + g * 16) ^ ((l15 & 7) << 4)];
        o[jd] = MFMA_BF16(pa, bv, o[jd]);
      }
    }
    __syncthreads();
  }

  // ---- normalize + write attn_out [B*T][1024] bf16 ----
  int b = bh >> 4, h = bh & 15;
#pragma unroll
  for (int jd = 0; jd < 4; jd++) {
#pragma unroll
    for (int r = 0; r < 4; r++) {
      int t = qlo + g * 4 + r;
      float vv = o[jd][r] / lsum[r];
      Oo[((size_t)(b * SEQT + t)) * DMODEL + h * 64 + jd * 16 + l15] = (bf16)vv;
    }
  }
}

// ---------------- launcher ----------------

extern "C" void kernel_launch(void* const* d_in, const int* in_sizes, int n_in,
                              void* d_out, int out_size, void* d_ws, size_t ws_size,
                              hipStream_t stream) {
  const float* x     = (const float*)d_in[0];
  const float* w_qkv = (const float*)d_in[1];
  const float* b_qkv = (const float*)d_in[2];
  const float* w_out = (const float*)d_in[3];
  const float* b_out = (const float*)d_in[4];
  float* out = (float*)d_out;

  char* ws = (char*)d_ws;
  bf16* xb    = (bf16*)(ws);                        // 16 MiB (reused as attn_out)
  bf16* wqkvT = (bf16*)(ws + (16u << 20));          //  6 MiB
  bf16* woutT = (bf16*)(ws + (22u << 20));          //  2 MiB
  bf16* Qb    = (bf16*)(ws + (24u << 20));          // 16 MiB
  bf16* Kb    = (bf16*)(ws + (40u << 20));          // 16 MiB
  bf16* Vb    = (bf16*)(ws + (56u << 20));          // 16 MiB
  bf16* VTb   = (bf16*)(ws + (72u << 20));          // 16 MiB (total 88 MiB)
  bf16* attn_o = xb;                                // xb dead after QKV GEMM

  k_cvt_f32_bf16<<<(MROWS * DMODEL / 8 + 255) / 256, 256, 0, stream>>>(x, xb, MROWS * DMODEL / 8);
  k_transpose_f32_bf16<<<16 * 48, 256, 0, stream>>>(w_qkv, wqkvT, DMODEL, 3 * DMODEL);
  k_transpose_f32_bf16<<<16 * 16, 256, 0, stream>>>(w_out, woutT, DMODEL, DMODEL);
  k_gemm_qkv<<<64 * 24, 256, 0, stream>>>(xb, wqkvT, b_qkv, Qb, Kb, Vb);
  k_transpose_v<<<64 * 32, 256, 0, stream>>>(Vb, VTb);
  k_attn<<<32 * 64, 256, 0, stream>>>(Qb, Kb, VTb, attn_o);
  k_gemm_out<<<64 * 8, 256, 0, stream>>>(attn_o, woutT, b_out, out);
}

// Round 2
// 306.803 us; speedup vs baseline: 1.0476x; 1.0476x over previous
//
#include <hip/hip_runtime.h>
#include <hip/hip_bf16.h>
#include <math.h>

// Problem constants
#define NHEADS 16
#define HDIM   64
#define SEQT   2048
#define NBATCH 4
#define DMODEL 1024
#define MROWS  (NBATCH * SEQT)   // 8192

typedef __bf16 bf16;
typedef bf16  bf16x8 __attribute__((ext_vector_type(8)));
typedef float f32x4  __attribute__((ext_vector_type(4)));

#define MFMA_BF16(a, b, c) __builtin_amdgcn_mfma_f32_16x16x32_bf16((a), (b), (c), 0, 0, 0)

__device__ __forceinline__ void gload_lds16(const void* g, void* l) {
  __builtin_amdgcn_global_load_lds((const __attribute__((address_space(1))) void*)g,
                                   (__attribute__((address_space(3))) void*)l, 16, 0, 0);
}

// ---------------- conversion / transpose pre-passes ----------------

__global__ __launch_bounds__(256) void k_cvt_f32_bf16(const float* __restrict__ in,
                                                      bf16* __restrict__ out, int n8) {
  int i = blockIdx.x * blockDim.x + threadIdx.x;
  if (i >= n8) return;
  const float4* in4 = (const float4*)in;
  float4 a = in4[(size_t)i * 2], b = in4[(size_t)i * 2 + 1];
  bf16x8 v;
  v[0] = (bf16)a.x; v[1] = (bf16)a.y; v[2] = (bf16)a.z; v[3] = (bf16)a.w;
  v[4] = (bf16)b.x; v[5] = (bf16)b.y; v[6] = (bf16)b.z; v[7] = (bf16)b.w;
  *(bf16x8*)(out + (size_t)i * 8) = v;
}

// in [R][C] f32  ->  out [C][R] bf16 ; tile 64x64 ; grid = (R/64)*(C/64)
__global__ __launch_bounds__(256) void k_transpose_f32_bf16(const float* __restrict__ in,
                                                            bf16* __restrict__ out,
                                                            int R, int C) {
  int nct = C >> 6;
  int rt = blockIdx.x / nct, ct = blockIdx.x % nct;
  __shared__ float tile[64][65];
  int tid = threadIdx.x;
#pragma unroll
  for (int i = 0; i < 16; i++) {
    int e = i * 256 + tid, r = e >> 6, c = e & 63;
    tile[r][c] = in[(size_t)(rt * 64 + r) * C + ct * 64 + c];
  }
  __syncthreads();
#pragma unroll
  for (int i = 0; i < 16; i++) {
    int e = i * 256 + tid, r = e >> 6, c = e & 63;
    out[(size_t)(ct * 64 + r) * R + rt * 64 + c] = (bf16)tile[c][r];
  }
}

// v: [BH][T][64] bf16 -> vt: [BH][64][T] bf16 ; tile 64x64 ; grid = BH*(T/64)
__global__ __launch_bounds__(256) void k_transpose_v(const bf16* __restrict__ v,
                                                     bf16* __restrict__ vt) {
  int tt = blockIdx.x & 31;     // T/64 = 32
  int bh = blockIdx.x >> 5;
  __shared__ bf16 tile[64][65];
  int tid = threadIdx.x;
  const bf16* src = v + (size_t)bh * SEQT * 64 + (size_t)tt * 64 * 64;
#pragma unroll
  for (int i = 0; i < 16; i++) {
    int e = i * 256 + tid, r = e >> 6, c = e & 63;
    tile[r][c] = src[r * 64 + c];
  }
  __syncthreads();
  bf16* dst = vt + (size_t)bh * 64 * SEQT + tt * 64;
#pragma unroll
  for (int i = 0; i < 16; i++) {
    int e = i * 256 + tid, r = e >> 6, c = e & 63;   // r = d, c = t-within-tile
    dst[(size_t)r * SEQT + c] = tile[c][r];
  }
}

// ---------------- m97-structure 128x128 GEMM core (BK=32) ----------------

__device__ __forceinline__ void gemm128_core(const bf16* __restrict__ A,
                                             const bf16* __restrict__ Bt,
                                             int K, int bm, int bn, char* smem,
                                             f32x4 (&acc)[4][4]) {
  int tid = threadIdx.x, lane = tid & 63, w = tid >> 6;
  int l15 = lane & 15, g = lane >> 4;
  int wrow = (w >> 1) * 64, wcol = (w & 1) * 64;
  char* As = smem;
  char* Bs = smem + 8192;
  const char* Ag = (const char*)(A + (size_t)bm * 128 * K);
  const char* Bg = (const char*)(Bt + (size_t)bn * 128 * K);
  const int rowB = K * 2;               // global row stride in bytes
  int srow = w * 16 + (lane >> 2);      // row within 64-row issue chunk
  int scol = (lane & 3) * 16;           // byte within 64B LDS row

  for (int kt = 0; kt < K / 32; kt++) {
#pragma unroll
    for (int is = 0; is < 2; is++) {
      int row = is * 64 + srow;
      gload_lds16(Ag + (size_t)row * rowB + kt * 64 + scol, As + is * 4096 + w * 1024);
      gload_lds16(Bg + (size_t)row * rowB + kt * 64 + scol, Bs + is * 4096 + w * 1024);
    }
    __syncthreads();
    bf16x8 af[4], bfr[4];
#pragma unroll
    for (int i = 0; i < 4; i++)
      af[i] = *(const bf16x8*)&As[(wrow + i * 16 + l15) * 64 + g * 16];
#pragma unroll
    for (int j = 0; j < 4; j++)
      bfr[j] = *(const bf16x8*)&Bs[(wcol + j * 16 + l15) * 64 + g * 16];
#pragma unroll
    for (int i = 0; i < 4; i++)
#pragma unroll
      for (int j = 0; j < 4; j++)
        acc[i][j] = MFMA_BF16(af[i], bfr[j], acc[i][j]);
    __syncthreads();
  }
}

__global__ __launch_bounds__(256) void k_gemm_qkv(const bf16* __restrict__ A,
                                                  const bf16* __restrict__ Bt,
                                                  const float* __restrict__ bias,
                                                  bf16* __restrict__ Qo,
                                                  bf16* __restrict__ Ko,
                                                  bf16* __restrict__ Vo) {
  const int K = DMODEL, NB = 24;        // N/128 = 3072/128
  int bm = blockIdx.x / NB, bn = blockIdx.x % NB;
  __shared__ __align__(16) char smem[16384];
  f32x4 acc[4][4] = {};
  gemm128_core(A, Bt, K, bm, bn, smem, acc);

  int tid = threadIdx.x, lane = tid & 63, w = tid >> 6;
  int l15 = lane & 15, g = lane >> 4;
  int wrow = (w >> 1) * 64, wcol = (w & 1) * 64;
  int rowbase = bm * 128 + wrow;
  int b = (bm * 128) >> 11;             // batch (T=2048 | 128-row blocks)
#pragma unroll
  for (int j = 0; j < 4; j++) {
    int n = bn * 128 + wcol + j * 16 + l15;      // 0..3071
    float bj = bias[n];
    int which = n >> 10;                          // 0=Q 1=K 2=V
    int nn = n & 1023;
    int head = nn >> 6, d = nn & 63;
    bf16* dst = (which == 0) ? Qo : (which == 1) ? Ko : Vo;
    size_t base = ((size_t)(b * NHEADS + head) * SEQT) * 64 + d;
#pragma unroll
    for (int i = 0; i < 4; i++) {
#pragma unroll
      for (int r = 0; r < 4; r++) {
        int row = rowbase + i * 16 + g * 4 + r;  // global m row
        int t = row & (SEQT - 1);
        dst[base + (size_t)t * 64] = (bf16)(acc[i][j][r] + bj);
      }
    }
  }
}

__global__ __launch_bounds__(256) void k_gemm_out(const bf16* __restrict__ A,
                                                  const bf16* __restrict__ Bt,
                                                  const float* __restrict__ bias,
                                                  float* __restrict__ C) {
  const int K = DMODEL, NB = 8;         // N/128 = 1024/128
  int bm = blockIdx.x / NB, bn = blockIdx.x % NB;
  __shared__ __align__(16) char smem[16384];
  f32x4 acc[4][4] = {};
  gemm128_core(A, Bt, K, bm, bn, smem, acc);

  int tid = threadIdx.x, lane = tid & 63, w = tid >> 6;
  int l15 = lane & 15, g = lane >> 4;
  int wrow = (w >> 1) * 64, wcol = (w & 1) * 64;
#pragma unroll
  for (int j = 0; j < 4; j++) {
    int n = bn * 128 + wcol + j * 16 + l15;
    float bj = bias[n];
#pragma unroll
    for (int i = 0; i < 4; i++) {
#pragma unroll
      for (int r = 0; r < 4; r++) {
        int row = bm * 128 + wrow + i * 16 + g * 4 + r;
        C[(size_t)row * DMODEL + n] = acc[i][j][r] + bj;
      }
    }
  }
}

// ---------------- flash attention (causal), bf16 MFMA ----------------
// Q,K: [BH][T][64] bf16 ; VT: [BH][64][T] bf16 ; out: [B*T][1024] bf16.
// Grid: (T/64)*BH, 256 threads = 4 waves; wave w owns q rows [qi*64+w*16, +16).
// Changes vs R1: (1) longest-first block order (qi descending) to kill the
// drain-tail; (2) double-buffered K/V staging, ONE barrier per KV tile,
// STAGE(j+1) issued right after the barrier so HBM latency hides under
// compute(j); (3) defer-max (T13): skip O-rescale unless any row max grew >8.

__global__ __launch_bounds__(256) void k_attn(const bf16* __restrict__ Q,
                                              const bf16* __restrict__ Kg,
                                              const bf16* __restrict__ VT,
                                              bf16* __restrict__ Oo) {
  int bh = blockIdx.x & 63;
  int qi = 31 - (blockIdx.x >> 6);      // longest-first
  int tid = threadIdx.x, lane = tid & 63, w = tid >> 6;
  int l15 = lane & 15, g = lane >> 4;
  __shared__ __align__(16) char smem[40960];  // K dbuf 2x8K | V dbuf 2x8K | P 4x2K
  char* Ps = smem + 32768 + w * 2048;

  const bf16* Qbh = Q  + (size_t)bh * SEQT * 64;
  const char* Kbyte = (const char*)(Kg + (size_t)bh * SEQT * 64);
  const char* Vbyte = (const char*)(VT + (size_t)bh * 64 * SEQT);
  int qlo = qi * 64 + w * 16;

  // staging addresses (loop-invariant): phys LDS offset -> swizzled source
  int pA = w * 1024 + lane * 16;        // is=0 phys byte in 8K tile
  int pB = pA + 4096;                   // is=1
  int rA = pA >> 7, rB = pB >> 7;       // tile row (kv for K, d for V)
  int lgA = pA ^ ((rA & 7) << 4), lgB = pB ^ ((rB & 7) << 4);
  int vA = rA * 4096 + (lgA & 127), vB = rB * 4096 + (lgB & 127);
  int dstA = w * 1024, dstB = 4096 + w * 1024;

  // Q fragments, pre-scaled by 1/sqrt(64)=0.125 (exact in bf16)
  bf16x8 aq[2];
#pragma unroll
  for (int ks = 0; ks < 2; ks++) {
    bf16x8 v = *(const bf16x8*)(Qbh + (size_t)(qlo + l15) * 64 + ks * 32 + g * 8);
#pragma unroll
    for (int e = 0; e < 8; e++) v[e] = (bf16)((float)v[e] * 0.125f);
    aq[ks] = v;
  }

  float m[4], lsum[4];
  f32x4 o[4];
#pragma unroll
  for (int r = 0; r < 4; r++) { m[r] = -INFINITY; lsum[r] = 0.f; }
#pragma unroll
  for (int jd = 0; jd < 4; jd++) o[jd] = (f32x4){0.f, 0.f, 0.f, 0.f};

  // prologue: stage tile 0 into buffer 0
  {
    gload_lds16(Kbyte + lgA, smem + dstA);
    gload_lds16(Kbyte + lgB, smem + dstB);
    gload_lds16(Vbyte + vA, smem + 16384 + dstA);
    gload_lds16(Vbyte + vB, smem + 16384 + dstB);
  }

  int cur = 0;
  for (int j = 0; j <= qi; j++) {
    __syncthreads();   // stage(j) landed for all waves; compute(j-1) done by all
    if (j < qi) {      // issue stage(j+1) into the other buffer; hides under compute
      int nx = cur ^ 1;
      const char* kg = Kbyte + (size_t)(j + 1) * 8192;
      const char* vg = Vbyte + (size_t)(j + 1) * 128;
      gload_lds16(kg + lgA, smem + nx * 8192 + dstA);
      gload_lds16(kg + lgB, smem + nx * 8192 + dstB);
      gload_lds16(vg + vA, smem + 16384 + nx * 8192 + dstA);
      gload_lds16(vg + vB, smem + 16384 + nx * 8192 + dstB);
    }
    char* Ks = smem + cur * 8192;
    char* Vs = smem + 16384 + cur * 8192;

    // ---- S = (Q*scale) @ K^T : 4 column tiles of 16 kv each ----
    f32x4 s[4];
#pragma unroll
    for (int c = 0; c < 4; c++) {
      int row = c * 16 + l15;
      f32x4 t = {0.f, 0.f, 0.f, 0.f};
      t = MFMA_BF16(aq[0], *(const bf16x8*)&Ks[(row * 128 + 0  + g * 16) ^ ((l15 & 7) << 4)], t);
      t = MFMA_BF16(aq[1], *(const bf16x8*)&Ks[(row * 128 + 64 + g * 16) ^ ((l15 & 7) << 4)], t);
      s[c] = t;
    }

    // ---- causal mask + row maxes ----
    bool diag = (j == qi);
    int qrb = w * 16 + g * 4;           // q row within 64-block, + r
    float mx[4];
#pragma unroll
    for (int r = 0; r < 4; r++) {
      float v0 = -INFINITY;
#pragma unroll
      for (int c = 0; c < 4; c++) {
        float v = s[c][r];
        if (diag && (c * 16 + l15) > (qrb + r)) { v = -INFINITY; s[c][r] = v; }
        v0 = fmaxf(v0, v);
      }
      v0 = fmaxf(v0, __shfl_xor(v0, 1));
      v0 = fmaxf(v0, __shfl_xor(v0, 2));
      v0 = fmaxf(v0, __shfl_xor(v0, 4));
      v0 = fmaxf(v0, __shfl_xor(v0, 8));
      mx[r] = v0;
    }

    // ---- defer-max: rescale only if any row max grew by >8 ----
    bool need = (mx[0] > m[0] + 8.f) | (mx[1] > m[1] + 8.f) |
                (mx[2] > m[2] + 8.f) | (mx[3] > m[3] + 8.f);
    if (__any(need)) {
#pragma unroll
      for (int r = 0; r < 4; r++) {
        float mn = fmaxf(m[r], mx[r]);
        float co = __expf(m[r] - mn);
        m[r] = mn;
        lsum[r] *= co;
#pragma unroll
        for (int jd = 0; jd < 4; jd++) o[jd][r] *= co;
      }
    }

    // ---- exp + row sums ----
#pragma unroll
    for (int r = 0; r < 4; r++) {
      float ssum = 0.f;
#pragma unroll
      for (int c = 0; c < 4; c++) {
        float p = __expf(s[c][r] - m[r]);
        s[c][r] = p;
        ssum += p;
      }
      ssum += __shfl_xor(ssum, 1);
      ssum += __shfl_xor(ssum, 2);
      ssum += __shfl_xor(ssum, 4);
      ssum += __shfl_xor(ssum, 8);
      lsum[r] += ssum;
    }

    // ---- P -> per-wave LDS (bf16, swizzled) ----
#pragma unroll
    for (int c = 0; c < 4; c++) {
#pragma unroll
      for (int r = 0; r < 4; r++) {
        int row = g * 4 + r;
        int addr = (row * 128 + (c * 16 + l15) * 2) ^ ((row & 7) << 4);
        *(bf16*)&Ps[addr] = (bf16)s[c][r];
      }
    }

    // ---- O += P @ V ----
#pragma unroll
    for (int ks = 0; ks < 2; ks++) {
      bf16x8 pa = *(const bf16x8*)&Ps[(l15 * 128 + ks * 64 + g * 16) ^ ((l15 & 7) << 4)];
#pragma unroll
      for (int jd = 0; jd < 4; jd++) {
        int vrow = jd * 16 + l15;
        bf16x8 bv = *(const bf16x8*)&Vs[(vrow * 128 + ks * 64 + g * 16) ^ ((l15 & 7) << 4)];
        o[jd] = MFMA_BF16(pa, bv, o[jd]);
      }
    }
    cur ^= 1;
  }

  // ---- normalize + write attn_out [B*T][1024] bf16 ----
  int b = bh >> 4, h = bh & 15;
#pragma unroll
  for (int jd = 0; jd < 4; jd++) {
#pragma unroll
    for (int r = 0; r < 4; r++) {
      int t = qlo + g * 4 + r;
      float vv = o[jd][r] / lsum[r];
      Oo[((size_t)(b * SEQT + t)) * DMODEL + h * 64 + jd * 16 + l15] = (bf16)vv;
    }
  }
}

// ---------------- launcher ----------------

extern "C" void kernel_launch(void* const* d_in, const int* in_sizes, int n_in,
                              void* d_out, int out_size, void* d_ws, size_t ws_size,
                              hipStream_t stream) {
  const float* x     = (const float*)d_in[0];
  const float* w_qkv = (const float*)d_in[1];
  const float* b_qkv = (const float*)d_in[2];
  const float* w_out = (const float*)d_in[3];
  const float* b_out = (const float*)d_in[4];
  float* out = (float*)d_out;

  char* ws = (char*)d_ws;
  bf16* xb    = (bf16*)(ws);                        // 16 MiB (reused as attn_out)
  bf16* wqkvT = (bf16*)(ws + (16u << 20));          //  6 MiB
  bf16* woutT = (bf16*)(ws + (22u << 20));          //  2 MiB
  bf16* Qb    = (bf16*)(ws + (24u << 20));          // 16 MiB
  bf16* Kb    = (bf16*)(ws + (40u << 20));          // 16 MiB
  bf16* Vb    = (bf16*)(ws + (56u << 20));          // 16 MiB
  bf16* VTb   = (bf16*)(ws + (72u << 20));          // 16 MiB (total 88 MiB)
  bf16* attn_o = xb;                                // xb dead after QKV GEMM

  k_cvt_f32_bf16<<<(MROWS * DMODEL / 8 + 255) / 256, 256, 0, stream>>>(x, xb, MROWS * DMODEL / 8);
  k_transpose_f32_bf16<<<16 * 48, 256, 0, stream>>>(w_qkv, wqkvT, DMODEL, 3 * DMODEL);
  k_transpose_f32_bf16<<<16 * 16, 256, 0, stream>>>(w_out, woutT, DMODEL, DMODEL);
  k_gemm_qkv<<<64 * 24, 256, 0, stream>>>(xb, wqkvT, b_qkv, Qb, Kb, Vb);
  k_transpose_v<<<64 * 32, 256, 0, stream>>>(Vb, VTb);
  k_attn<<<32 * 64, 256, 0, stream>>>(Qb, Kb, VTb, attn_o);
  k_gemm_out<<<64 * 8, 256, 0, stream>>>(attn_o, woutT, b_out, out);
}

// Round 3
// 261.673 us; speedup vs baseline: 1.2283x; 1.1725x over previous
//
#include <hip/hip_runtime.h>
#include <hip/hip_bf16.h>
#include <math.h>

// Problem constants
#define NHEADS 16
#define HDIM   64
#define SEQT   2048
#define NBATCH 4
#define DMODEL 1024
#define MROWS  (NBATCH * SEQT)   // 8192

typedef __bf16 bf16;
typedef bf16  bf16x8 __attribute__((ext_vector_type(8)));
typedef float f32x4  __attribute__((ext_vector_type(4)));
typedef float f32x16 __attribute__((ext_vector_type(16)));
typedef unsigned int u32x4 __attribute__((ext_vector_type(4)));

#define MFMA_BF16(a, b, c) __builtin_amdgcn_mfma_f32_16x16x32_bf16((a), (b), (c), 0, 0, 0)
#define MFMA32(a, b, c)    __builtin_amdgcn_mfma_f32_32x32x16_bf16((a), (b), (c), 0, 0, 0)
#define Z16 {0.f,0.f,0.f,0.f,0.f,0.f,0.f,0.f,0.f,0.f,0.f,0.f,0.f,0.f,0.f,0.f}

__device__ __forceinline__ void gload_lds16(const void* g, void* l) {
  __builtin_amdgcn_global_load_lds((const __attribute__((address_space(1))) void*)g,
                                   (__attribute__((address_space(3))) void*)l, 16, 0, 0);
}

__device__ __forceinline__ unsigned cvtpk_bf16(float lo, float hi) {
  unsigned r;
  asm("v_cvt_pk_bf16_f32 %0, %1, %2" : "=v"(r) : "v"(lo), "v"(hi));
  return r;
}
__device__ __forceinline__ void plswap(unsigned& a, unsigned& b) {
  asm volatile("v_permlane32_swap_b32 %0, %1" : "+v"(a), "+v"(b));
}

// ---------------- conversion / transpose pre-passes ----------------

__global__ __launch_bounds__(256) void k_cvt_f32_bf16(const float* __restrict__ in,
                                                      bf16* __restrict__ out, int n8) {
  int i = blockIdx.x * blockDim.x + threadIdx.x;
  if (i >= n8) return;
  const float4* in4 = (const float4*)in;
  float4 a = in4[(size_t)i * 2], b = in4[(size_t)i * 2 + 1];
  bf16x8 v;
  v[0] = (bf16)a.x; v[1] = (bf16)a.y; v[2] = (bf16)a.z; v[3] = (bf16)a.w;
  v[4] = (bf16)b.x; v[5] = (bf16)b.y; v[6] = (bf16)b.z; v[7] = (bf16)b.w;
  *(bf16x8*)(out + (size_t)i * 8) = v;
}

__global__ __launch_bounds__(256) void k_transpose_f32_bf16(const float* __restrict__ in,
                                                            bf16* __restrict__ out,
                                                            int R, int C) {
  int nct = C >> 6;
  int rt = blockIdx.x / nct, ct = blockIdx.x % nct;
  __shared__ float tile[64][65];
  int tid = threadIdx.x;
#pragma unroll
  for (int i = 0; i < 16; i++) {
    int e = i * 256 + tid, r = e >> 6, c = e & 63;
    tile[r][c] = in[(size_t)(rt * 64 + r) * C + ct * 64 + c];
  }
  __syncthreads();
#pragma unroll
  for (int i = 0; i < 16; i++) {
    int e = i * 256 + tid, r = e >> 6, c = e & 63;
    out[(size_t)(ct * 64 + r) * R + rt * 64 + c] = (bf16)tile[c][r];
  }
}

__global__ __launch_bounds__(256) void k_transpose_v(const bf16* __restrict__ v,
                                                     bf16* __restrict__ vt) {
  int tt = blockIdx.x & 31;     // T/64 = 32
  int bh = blockIdx.x >> 5;
  __shared__ bf16 tile[64][65];
  int tid = threadIdx.x;
  const bf16* src = v + (size_t)bh * SEQT * 64 + (size_t)tt * 64 * 64;
#pragma unroll
  for (int i = 0; i < 16; i++) {
    int e = i * 256 + tid, r = e >> 6, c = e & 63;
    tile[r][c] = src[r * 64 + c];
  }
  __syncthreads();
  bf16* dst = vt + (size_t)bh * 64 * SEQT + tt * 64;
#pragma unroll
  for (int i = 0; i < 16; i++) {
    int e = i * 256 + tid, r = e >> 6, c = e & 63;   // r = d, c = t-within-tile
    dst[(size_t)r * SEQT + c] = tile[c][r];
  }
}

// ---------------- m97-structure 128x128 GEMM core (BK=32) ----------------

__device__ __forceinline__ void gemm128_core(const bf16* __restrict__ A,
                                             const bf16* __restrict__ Bt,
                                             int K, int bm, int bn, char* smem,
                                             f32x4 (&acc)[4][4]) {
  int tid = threadIdx.x, lane = tid & 63, w = tid >> 6;
  int l15 = lane & 15, g = lane >> 4;
  int wrow = (w >> 1) * 64, wcol = (w & 1) * 64;
  char* As = smem;
  char* Bs = smem + 8192;
  const char* Ag = (const char*)(A + (size_t)bm * 128 * K);
  const char* Bg = (const char*)(Bt + (size_t)bn * 128 * K);
  const int rowB = K * 2;
  int srow = w * 16 + (lane >> 2);
  int scol = (lane & 3) * 16;

  for (int kt = 0; kt < K / 32; kt++) {
#pragma unroll
    for (int is = 0; is < 2; is++) {
      int row = is * 64 + srow;
      gload_lds16(Ag + (size_t)row * rowB + kt * 64 + scol, As + is * 4096 + w * 1024);
      gload_lds16(Bg + (size_t)row * rowB + kt * 64 + scol, Bs + is * 4096 + w * 1024);
    }
    __syncthreads();
    bf16x8 af[4], bfr[4];
#pragma unroll
    for (int i = 0; i < 4; i++)
      af[i] = *(const bf16x8*)&As[(wrow + i * 16 + l15) * 64 + g * 16];
#pragma unroll
    for (int j = 0; j < 4; j++)
      bfr[j] = *(const bf16x8*)&Bs[(wcol + j * 16 + l15) * 64 + g * 16];
#pragma unroll
    for (int i = 0; i < 4; i++)
#pragma unroll
      for (int j = 0; j < 4; j++)
        acc[i][j] = MFMA_BF16(af[i], bfr[j], acc[i][j]);
    __syncthreads();
  }
}

__global__ __launch_bounds__(256) void k_gemm_qkv(const bf16* __restrict__ A,
                                                  const bf16* __restrict__ Bt,
                                                  const float* __restrict__ bias,
                                                  bf16* __restrict__ Qo,
                                                  bf16* __restrict__ Ko,
                                                  bf16* __restrict__ Vo) {
  const int K = DMODEL, NB = 24;
  int bm = blockIdx.x / NB, bn = blockIdx.x % NB;
  __shared__ __align__(16) char smem[16384];
  f32x4 acc[4][4] = {};
  gemm128_core(A, Bt, K, bm, bn, smem, acc);

  int tid = threadIdx.x, lane = tid & 63, w = tid >> 6;
  int l15 = lane & 15, g = lane >> 4;
  int wrow = (w >> 1) * 64, wcol = (w & 1) * 64;
  int rowbase = bm * 128 + wrow;
  int b = (bm * 128) >> 11;
#pragma unroll
  for (int j = 0; j < 4; j++) {
    int n = bn * 128 + wcol + j * 16 + l15;
    float bj = bias[n];
    int which = n >> 10;
    int nn = n & 1023;
    int head = nn >> 6, d = nn & 63;
    bf16* dst = (which == 0) ? Qo : (which == 1) ? Ko : Vo;
    size_t base = ((size_t)(b * NHEADS + head) * SEQT) * 64 + d;
#pragma unroll
    for (int i = 0; i < 4; i++) {
#pragma unroll
      for (int r = 0; r < 4; r++) {
        int row = rowbase + i * 16 + g * 4 + r;
        int t = row & (SEQT - 1);
        dst[base + (size_t)t * 64] = (bf16)(acc[i][j][r] + bj);
      }
    }
  }
}

__global__ __launch_bounds__(256) void k_gemm_out(const bf16* __restrict__ A,
                                                  const bf16* __restrict__ Bt,
                                                  const float* __restrict__ bias,
                                                  float* __restrict__ C) {
  const int K = DMODEL, NB = 8;
  int bm = blockIdx.x / NB, bn = blockIdx.x % NB;
  __shared__ __align__(16) char smem[16384];
  f32x4 acc[4][4] = {};
  gemm128_core(A, Bt, K, bm, bn, smem, acc);

  int tid = threadIdx.x, lane = tid & 63, w = tid >> 6;
  int l15 = lane & 15, g = lane >> 4;
  int wrow = (w >> 1) * 64, wcol = (w & 1) * 64;
#pragma unroll
  for (int j = 0; j < 4; j++) {
    int n = bn * 128 + wcol + j * 16 + l15;
    float bj = bias[n];
#pragma unroll
    for (int i = 0; i < 4; i++) {
#pragma unroll
      for (int r = 0; r < 4; r++) {
        int row = bm * 128 + wrow + i * 16 + g * 4 + r;
        C[(size_t)row * DMODEL + n] = acc[i][j][r] + bj;
      }
    }
  }
}

// ---------------- flash attention (causal), swapped-QK 32x32 (m214-style) --
// Q,K: [BH][T][64] bf16 ; VT: [BH][64][T] bf16 ; out attn_o: [B*T][1024] bf16.
// Grid: (T/128)*BH = 1024 blocks, 256 threads = 4 waves; wave wv owns 32 q rows.
// S^T = mfma32x32x16(K_frag, Q_frag): lane owns q = qbase+(l&31); kv axis lives
// in 32 regs (16 per 32-kv half, rows (r&3)+8*(r>>2)+4*(l>>5)). Softmax is
// in-lane + one shfl_xor(32). P->bf16 A-frags via v_cvt_pk_bf16_f32 +
// v_permlane32_swap_b32 (no LDS round trip). O frag: lane owns d = (l&31)+32dh,
// 16 q rows; per-row factors fetched by __shfl on the rare rescale + epilogue.

__global__ __launch_bounds__(256) void k_attn(const bf16* __restrict__ Q,
                                              const bf16* __restrict__ Kg,
                                              const bf16* __restrict__ VT,
                                              bf16* __restrict__ Oo) {
  int bh = blockIdx.x & 63;
  int qi = 15 - (blockIdx.x >> 6);      // longest-first, 0..15
  int tid = threadIdx.x, lane = tid & 63, wv = tid >> 6;
  int l31 = lane & 31, hi = lane >> 5;
  __shared__ __align__(16) char smem[32768];   // K dbuf 2x8K | V dbuf 2x8K

  const bf16* Qbh = Q + (size_t)bh * SEQT * 64;
  const char* Kbyte = (const char*)(Kg + (size_t)bh * SEQT * 64);
  const char* Vbyte = (const char*)(VT + (size_t)bh * 64 * SEQT);
  int qbase = qi * 128 + wv * 32;
  int ql = qbase + l31;                 // this lane's q row (softmax owner)

  // staging addresses (same verified pattern as before)
  int pA = tid * 16, pB = pA + 4096;
  int rA = pA >> 7, rB = pB >> 7;
  int lgA = pA ^ ((rA & 7) << 4), lgB = pB ^ ((rB & 7) << 4);
  int vA = rA * 4096 + (lgA & 127), vB = rB * 4096 + (lgB & 127);

  // Q fragments (B-operand): lane l holds Q[ql][d = s*16 + hi*8 + e], e=0..7
  bf16x8 qf[4];
#pragma unroll
  for (int s = 0; s < 4; s++) {
    bf16x8 v = *(const bf16x8*)(Qbh + (size_t)ql * 64 + s * 16 + hi * 8);
#pragma unroll
    for (int e = 0; e < 8; e++) v[e] = (bf16)((float)v[e] * 0.125f);
    qf[s] = v;
  }

  float m = -INFINITY, lsum = 0.f;      // per-lane (per-q); lsum is half-row partial
  f32x16 o[2] = {Z16, Z16};

  // prologue: stage tile 0 into buffer 0
  gload_lds16(Kbyte + lgA, smem + pA);
  gload_lds16(Kbyte + lgB, smem + pB);
  gload_lds16(Vbyte + vA, smem + 16384 + pA);
  gload_lds16(Vbyte + vB, smem + 16384 + pB);

  int NT = 2 * qi + 2, cur = 0;
  for (int j = 0; j < NT; j++) {
    __syncthreads();                    // stage(j) landed; compute(j-1) done
    if (j + 1 < NT) {
      int nx = cur ^ 1;
      const char* kg = Kbyte + (size_t)(j + 1) * 8192;
      const char* vg = Vbyte + (size_t)(j + 1) * 128;
      gload_lds16(kg + lgA, smem + nx * 8192 + pA);
      gload_lds16(kg + lgB, smem + nx * 8192 + pB);
      gload_lds16(vg + vA, smem + 16384 + nx * 8192 + pA);
      gload_lds16(vg + vB, smem + 16384 + nx * 8192 + pB);
    }
    if (j * 64 <= qbase + 31) {         // wave has unmasked work in this tile
      const char* Ks = smem + cur * 8192;
      const char* Vs = smem + 16384 + cur * 8192;

      // ---- S^T halves: st[h] = K[32h..32h+31] @ Q^T ----
      f32x16 st[2];
#pragma unroll
      for (int h = 0; h < 2; h++) {
        f32x16 acc = Z16;
#pragma unroll
        for (int s = 0; s < 4; s++) {
          int row = h * 32 + l31;
          bf16x8 kf = *(const bf16x8*)&Ks[(row * 128 + s * 32 + hi * 16) ^ ((l31 & 7) << 4)];
          acc = MFMA32(kf, qf[s], acc);
        }
        st[h] = acc;
      }

      // ---- causal mask (only tiles overlapping the diagonal) ----
      if (j * 64 + 63 > qbase) {
        int rel = ql - (j * 64 + 4 * hi);
#pragma unroll
        for (int r = 0; r < 16; r++) {
          const int R0 = (r & 3) + 8 * (r >> 2);
          if (R0 > rel) st[0][r] = -INFINITY;
          if (R0 > rel - 32) st[1][r] = -INFINITY;
        }
      }

      // ---- row max: in-lane tree + one cross shfl ----
      float m0 = -INFINITY, m1 = -INFINITY, m2 = -INFINITY, m3 = -INFINITY;
#pragma unroll
      for (int h = 0; h < 2; h++)
#pragma unroll
        for (int r = 0; r < 16; r += 4) {
          m0 = fmaxf(m0, st[h][r]);
          m1 = fmaxf(m1, st[h][r + 1]);
          m2 = fmaxf(m2, st[h][r + 2]);
          m3 = fmaxf(m3, st[h][r + 3]);
        }
      float mx = fmaxf(fmaxf(m0, m1), fmaxf(m2, m3));
      mx = fmaxf(mx, __shfl_xor(mx, 32));

      // ---- defer-max rescale (rare) ----
      if (__any(mx > m + 8.f)) {
        float mn = fmaxf(m, mx), co = __expf(m - mn);
        m = mn; lsum *= co;
#pragma unroll
        for (int r = 0; r < 16; r++) {
          const int R0 = (r & 3) + 8 * (r >> 2);
          float fac = __shfl(co, R0 + 4 * hi);
          o[0][r] *= fac; o[1][r] *= fac;
        }
      }

      // ---- exp + partial row sum (this lane's 32 kv) ----
      float s0 = 0.f, s1 = 0.f, s2 = 0.f, s3 = 0.f;
#pragma unroll
      for (int h = 0; h < 2; h++)
#pragma unroll
        for (int r = 0; r < 16; r += 4) {
          float p0 = __expf(st[h][r] - m);     st[h][r] = p0;     s0 += p0;
          float p1 = __expf(st[h][r + 1] - m); st[h][r + 1] = p1; s1 += p1;
          float p2 = __expf(st[h][r + 2] - m); st[h][r + 2] = p2; s2 += p2;
          float p3 = __expf(st[h][r + 3] - m); st[h][r + 3] = p3; s3 += p3;
        }
      lsum += (s0 + s1) + (s2 + s3);

      // ---- pack P -> A-frags (16 cvt_pk + 8 permlane32_swap), then PV ----
#pragma unroll
      for (int h = 0; h < 2; h++) {
        unsigned pw[8];
#pragma unroll
        for (int i = 0; i < 8; i++) pw[i] = cvtpk_bf16(st[h][2 * i], st[h][2 * i + 1]);
        plswap(pw[0], pw[2]); plswap(pw[1], pw[3]);
        plswap(pw[4], pw[6]); plswap(pw[5], pw[7]);
        u32x4 f0 = {pw[0], pw[1], pw[2], pw[3]};
        u32x4 f1 = {pw[4], pw[5], pw[6], pw[7]};
        bf16x8 pa0 = __builtin_bit_cast(bf16x8, f0);   // kv slot 2h
        bf16x8 pa1 = __builtin_bit_cast(bf16x8, f1);   // kv slot 2h+1
#pragma unroll
        for (int dh = 0; dh < 2; dh++) {
          int vrow = dh * 32 + l31;
          bf16x8 bv0 = *(const bf16x8*)&Vs[(vrow * 128 + (2 * h) * 32 + hi * 16) ^ ((l31 & 7) << 4)];
          bf16x8 bv1 = *(const bf16x8*)&Vs[(vrow * 128 + (2 * h + 1) * 32 + hi * 16) ^ ((l31 & 7) << 4)];
          o[dh] = MFMA32(pa0, bv0, o[dh]);
          o[dh] = MFMA32(pa1, bv1, o[dh]);
        }
      }
    }
    cur ^= 1;
  }

  // ---- normalize + write attn_out [B*T][1024] bf16 ----
  float inv = 1.f / (lsum + __shfl_xor(lsum, 32));
  int b = bh >> 4, hd = bh & 15;
#pragma unroll
  for (int r = 0; r < 16; r++) {
    const int R0 = (r & 3) + 8 * (r >> 2);
    float fac = __shfl(inv, R0 + 4 * hi);
    int qrow = qbase + R0 + 4 * hi;
    size_t off = ((size_t)(b * SEQT + qrow)) * DMODEL + hd * 64;
    Oo[off + l31]      = (bf16)(o[0][r] * fac);
    Oo[off + 32 + l31] = (bf16)(o[1][r] * fac);
  }
}

// ---------------- launcher ----------------

extern "C" void kernel_launch(void* const* d_in, const int* in_sizes, int n_in,
                              void* d_out, int out_size, void* d_ws, size_t ws_size,
                              hipStream_t stream) {
  const float* x     = (const float*)d_in[0];
  const float* w_qkv = (const float*)d_in[1];
  const float* b_qkv = (const float*)d_in[2];
  const float* w_out = (const float*)d_in[3];
  const float* b_out = (const float*)d_in[4];
  float* out = (float*)d_out;

  char* ws = (char*)d_ws;
  bf16* xb    = (bf16*)(ws);                        // 16 MiB (reused as attn_out)
  bf16* wqkvT = (bf16*)(ws + (16u << 20));          //  6 MiB
  bf16* woutT = (bf16*)(ws + (22u << 20));          //  2 MiB
  bf16* Qb    = (bf16*)(ws + (24u << 20));          // 16 MiB
  bf16* Kb    = (bf16*)(ws + (40u << 20));          // 16 MiB
  bf16* Vb    = (bf16*)(ws + (56u << 20));          // 16 MiB
  bf16* VTb   = (bf16*)(ws + (72u << 20));          // 16 MiB (total 88 MiB)
  bf16* attn_o = xb;                                // xb dead after QKV GEMM

  k_cvt_f32_bf16<<<(MROWS * DMODEL / 8 + 255) / 256, 256, 0, stream>>>(x, xb, MROWS * DMODEL / 8);
  k_transpose_f32_bf16<<<16 * 48, 256, 0, stream>>>(w_qkv, wqkvT, DMODEL, 3 * DMODEL);
  k_transpose_f32_bf16<<<16 * 16, 256, 0, stream>>>(w_out, woutT, DMODEL, DMODEL);
  k_gemm_qkv<<<64 * 24, 256, 0, stream>>>(xb, wqkvT, b_qkv, Qb, Kb, Vb);
  k_transpose_v<<<64 * 32, 256, 0, stream>>>(Vb, VTb);
  k_attn<<<16 * 64, 256, 0, stream>>>(Qb, Kb, VTb, attn_o);
  k_gemm_out<<<64 * 8, 256, 0, stream>>>(attn_o, woutT, b_out, out);
}